// Round 18
// baseline (687.618 us; speedup 1.0000x reference)
//
#include <hip/hip_runtime.h>

typedef __bf16 bf16x8 __attribute__((ext_vector_type(8)));
typedef float f32x4 __attribute__((ext_vector_type(4)));
typedef float f32x16 __attribute__((ext_vector_type(16)));
typedef short short8 __attribute__((ext_vector_type(8)));

union S8 { short8 v; unsigned short u[8]; };

__device__ __forceinline__ float b2f(unsigned short u) {
    unsigned int x = ((unsigned int)u) << 16;
    float f; __builtin_memcpy(&f, &x, 4); return f;
}
__device__ __forceinline__ unsigned short f2b(float f) {
    unsigned int x; __builtin_memcpy(&x, &f, 4);
    unsigned int r = x + 0x7fffu + ((x >> 16) & 1u);   // RNE
    return (unsigned short)(r >> 16);
}
__device__ __forceinline__ unsigned pack2(float lo, float hi) {
    return (unsigned)f2b(lo) | ((unsigned)f2b(hi) << 16);
}

__device__ __forceinline__ void gload_lds16(const unsigned short* g, unsigned short* l) {
    __builtin_amdgcn_global_load_lds(
        (const __attribute__((address_space(1))) void*)g,
        (__attribute__((address_space(3))) void*)l, 16, 0, 0);
}

__device__ __forceinline__ void cvt4(const float* __restrict__ src, unsigned short* __restrict__ dst, long off) {
    float4 v = *(const float4*)(src + off);
    ushort4 u;
    u.x = f2b(v.x); u.y = f2b(v.y); u.z = f2b(v.z); u.w = f2b(v.w);
    *(ushort4*)(dst + off) = u;
}

// ---------------- merged prep + hs convert + QKV weight converts ----------------
__global__ void prep_cvt(const int* __restrict__ tt, const int* __restrict__ pos,
                         const float* __restrict__ invf,
                         unsigned char* __restrict__ mask,
                         float* __restrict__ ct, float* __restrict__ st, int S,
                         const float* __restrict__ hs, unsigned short* __restrict__ hbf, long nh,
                         const float* __restrict__ wqv, unsigned short* __restrict__ wqvb,
                         const float* __restrict__ wql, unsigned short* __restrict__ wqlb, long nw) {
    long tid = (long)blockIdx.x * 256 + threadIdx.x;
    if (tid < S * 64) {
        int s = (int)(tid >> 6), d = (int)(tid & 63);
        float f = (float)pos[s] * invf[d];
        ct[tid] = cosf(f);
        st[tid] = sinf(f);
        if (d == 0) mask[s] = (s < S - 1 && tt[s] == 1 && tt[s + 1] == 1) ? 1 : 0;
    }
    long stride = (long)gridDim.x * 256 * 4;
    for (long i = tid * 4; i < nh; i += stride) cvt4(hs, hbf, i);
    for (long i = tid * 4; i < nw; i += stride) cvt4(wqv, wqvb, i);
    for (long i = tid * 4; i < nw; i += stride) cvt4(wql, wqlb, i);
}

// ---------------- RoPE in-place on bf16 qkv ----------------
__global__ void rope_kernel(unsigned short* __restrict__ qkv,
                            const float* __restrict__ ct, const float* __restrict__ st, int S) {
    int i = blockIdx.x * 256 + threadIdx.x;
    if (i >= S * 32 * 2 * 8) return;
    int c  = i & 7;
    int qk = (i >> 3) & 1;
    int h  = (i >> 4) & 31;
    int s  = i >> 9;
    size_t base = (size_t)s * 12288 + (size_t)qk * 4096 + h * 128 + c * 8;
    S8 x1, x2, y1, y2;
    x1.v = *(const short8*)(qkv + base);
    x2.v = *(const short8*)(qkv + base + 64);
    #pragma unroll
    for (int j = 0; j < 8; ++j) {
        float cc = ct[s * 64 + c * 8 + j];
        float ss = st[s * 64 + c * 8 + j];
        float a = b2f(x1.u[j]), b = b2f(x2.u[j]);
        y1.u[j] = f2b(a * cc - b * ss);
        y2.u[j] = f2b(b * cc + a * ss);
    }
    *(short8*)(qkv + base)      = y1.v;
    *(short8*)(qkv + base + 64) = y2.v;
}

// ---------------- V transpose: qkv v-part [S][4096] -> vt [4096][S] ----------------
__global__ void transpose_v(const unsigned short* __restrict__ qkv,
                            unsigned short* __restrict__ vt, int S) {
    __shared__ unsigned short tile[64][72];
    int s0 = blockIdx.x * 64;
    int hd0 = blockIdx.y * 64;
    int t = threadIdx.x;
    #pragma unroll
    for (int it = 0; it < 2; ++it) {
        int c = it * 256 + t;
        int sl = c >> 3, k8 = (c & 7) << 3;
        S8 v; v.v = *(const short8*)(qkv + (size_t)(s0 + sl) * 12288 + 8192 + hd0 + k8);
        #pragma unroll
        for (int j = 0; j < 8; ++j) tile[sl][k8 + j] = v.u[j];
    }
    __syncthreads();
    #pragma unroll
    for (int it = 0; it < 2; ++it) {
        int c = it * 256 + t;
        int hdl = c >> 3, sk = (c & 7) << 3;
        S8 o;
        #pragma unroll
        for (int j = 0; j < 8; ++j) o.u[j] = tile[sk + j][hdl];
        *(short8*)(vt + (size_t)(hd0 + hdl) * S + s0 + sk) = o.v;
    }
}

// ---------------- dual-expert masked GEMM (round-11 proven, verbatim) ----------------
template <int OUT_BF16>
__global__ void __launch_bounds__(256, 2)
gemm_bt_dual(const unsigned short* __restrict__ A,
             const unsigned short* __restrict__ Bv,
             const unsigned short* __restrict__ Bl,
             void* __restrict__ Cv,
             int M, int N, int K,
             const unsigned char* __restrict__ mask) {
    __shared__ unsigned short sA[2 * 128 * 32];
    __shared__ unsigned short sB[2 * 128 * 32];
    __shared__ int s_any;
    int t = threadIdx.x;
    int expert = blockIdx.y >> 4;
    int m0 = (blockIdx.y & 15) * 128;
    int n0 = blockIdx.x * 128;
    int want = expert ? 0 : 1;
    const unsigned short* B = expert ? Bl : Bv;

    if (t == 0) s_any = 0;
    __syncthreads();
    if (t < 128 && mask[m0 + t] == (unsigned char)want) s_any = 1;
    __syncthreads();
    if (!s_any) return;

    int lane = t & 63;
    int w = t >> 6;
    int wm = w >> 1, wn = w & 1;
    int l15 = lane & 15, g = lane >> 4;

    int c0 = w * 2, c1 = c0 + 1;
    int r0 = c0 * 16 + (lane >> 2);
    int r1 = c1 * 16 + (lane >> 2);
    int pc = lane & 3;
    const unsigned short* gA0 = A + (size_t)(m0 + r0) * K + ((pc ^ ((r0 >> 1) & 3)) << 3);
    const unsigned short* gA1 = A + (size_t)(m0 + r1) * K + ((pc ^ ((r1 >> 1) & 3)) << 3);
    const unsigned short* gB0 = B + (size_t)(n0 + r0) * K + ((pc ^ ((r0 >> 1) & 3)) << 3);
    const unsigned short* gB1 = B + (size_t)(n0 + r1) * K + ((pc ^ ((r1 >> 1) & 3)) << 3);

    auto stage = [&](int buf, int k0) {
        unsigned short* bA = sA + buf * 4096;
        unsigned short* bB = sB + buf * 4096;
        gload_lds16(gA0 + k0, bA + c0 * 512);
        gload_lds16(gA1 + k0, bA + c1 * 512);
        gload_lds16(gB0 + k0, bB + c0 * 512);
        gload_lds16(gB1 + k0, bB + c1 * 512);
    };

    f32x4 acc[4][4];
    #pragma unroll
    for (int i = 0; i < 4; ++i)
        #pragma unroll
        for (int j = 0; j < 4; ++j) acc[i][j] = (f32x4){0.f, 0.f, 0.f, 0.f};

    stage(0, 0);
    __syncthreads();
    int cur = 0;

    for (int k0 = 0; k0 < K; k0 += 32) {
        if (k0 + 32 < K) stage(cur ^ 1, k0 + 32);
        const unsigned short* rA = sA + cur * 4096;
        const unsigned short* rB = sB + cur * 4096;
        bf16x8 af[4], bfr[4];
        #pragma unroll
        for (int i = 0; i < 4; ++i) {
            int ar = wm * 64 + i * 16 + l15;
            int ca = g ^ ((ar >> 1) & 3);
            af[i] = *(const bf16x8*)(rA + ar * 32 + ca * 8);
            int br = wn * 64 + i * 16 + l15;
            int cb = g ^ ((br >> 1) & 3);
            bfr[i] = *(const bf16x8*)(rB + br * 32 + cb * 8);
        }
        #pragma unroll
        for (int i = 0; i < 4; ++i)
            #pragma unroll
            for (int j = 0; j < 4; ++j)
                acc[i][j] = __builtin_amdgcn_mfma_f32_16x16x32_bf16(af[i], bfr[j], acc[i][j], 0, 0, 0);
        __syncthreads();
        cur ^= 1;
    }

    #pragma unroll
    for (int i = 0; i < 4; ++i) {
        int rbase = m0 + wm * 64 + i * 16 + g * 4;
        #pragma unroll
        for (int r = 0; r < 4; ++r) {
            int row = rbase + r;
            if (mask[row] != (unsigned char)want) continue;
            #pragma unroll
            for (int j = 0; j < 4; ++j) {
                int col = n0 + wn * 64 + j * 16 + l15;
                float vv = acc[i][j][r];
                if (OUT_BF16) ((unsigned short*)Cv)[(size_t)row * N + col] = f2b(vv);
                else          ((float*)Cv)[(size_t)row * N + col] = vv;
            }
        }
    }
}

// ---------------- flash attention + fused out-proj weight converts ----------------
// 1D grid, 2560 blocks x 128 threads: blocks 0..1023 = attn (bid decode identical
// to r17's proven 2-wave pairing); blocks 1024..2559 convert wov/wol f32->bf16,
// backfilling CU slots as attn blocks drain (attn runs at ~2% HBM -> free BW).
__global__ void __launch_bounds__(128, 2)
attn32(const unsigned short* __restrict__ qkv,
       const unsigned short* __restrict__ vt,
       unsigned short* __restrict__ ctx, int S,
       const float* __restrict__ wov, unsigned short* __restrict__ wovb,
       const float* __restrict__ wol, unsigned short* __restrict__ wolb, long nw) {
    const float scale = 0.08838834764831845f;  // 1/sqrt(128)
    const float NEG = -1e30f;
    int bid = blockIdx.x;

    if (bid >= 1024) {
        long i = ((long)(bid - 1024) * 128 + threadIdx.x) * 4;
        long stride = (long)1536 * 128 * 4;
        long tot = 2 * nw;
        for (; i < tot; i += stride) {
            if (i < nw) cvt4(wov, wovb, i);
            else        cvt4(wol, wolb, i - nw);
        }
        return;
    }

    int xg = bid & 7;                                 // XCD slot
    int j  = bid >> 3;                                // 0..127
    int h  = xg * 4 + (j >> 5);                       // 4 heads per XCD
    int p  = j & 31;                                  // pair index
    int w  = threadIdx.x >> 6;                        // wave in block
    int qc = w ? (63 - p) : p;
    int q0 = qc * 32;
    int l = threadIdx.x & 63;
    int l31 = l & 31, hi = l >> 5;

    bf16x8 qf[8];
    {
        const unsigned short* qb = qkv + (size_t)(q0 + l31) * 12288 + h * 128 + hi * 8;
        #pragma unroll
        for (int kk = 0; kk < 8; ++kk) qf[kk] = *(const bf16x8*)(qb + kk * 16);
    }

    f32x16 oacc[4];
    #pragma unroll
    for (int dc = 0; dc < 4; ++dc)
        #pragma unroll
        for (int r = 0; r < 16; ++r) oacc[dc][r] = 0.f;
    float m = NEG, ll = 0.f;

    int nfull = q0 >> 6;
    for (int kt = 0; kt <= nfull; ++kt) {
        int kb = kt << 6;
        bool partial = (kt == nfull);

        bf16x8 vf[16];
        #pragma unroll
        for (int dc = 0; dc < 4; ++dc) {
            const unsigned short* vb = vt + (size_t)(h * 128 + dc * 32 + l31) * S + kb + hi * 8;
            #pragma unroll
            for (int g2 = 0; g2 < 4; ++g2)
                vf[dc * 4 + g2] = *(const bf16x8*)(vb + g2 * 16);
        }

        f32x16 sacc[2];
        #pragma unroll
        for (int sub = 0; sub < 2; ++sub) {
            #pragma unroll
            for (int r = 0; r < 16; ++r) sacc[sub][r] = 0.f;
            const unsigned short* kp = qkv + (size_t)(kb + sub * 32 + l31) * 12288 + 4096 + h * 128 + hi * 8;
            bf16x8 kf[8];
            #pragma unroll
            for (int kk = 0; kk < 8; ++kk) kf[kk] = *(const bf16x8*)(kp + kk * 16);
            __builtin_amdgcn_s_setprio(1);
            #pragma unroll
            for (int kk = 0; kk < 8; ++kk)
                sacc[sub] = __builtin_amdgcn_mfma_f32_32x32x16_bf16(kf[kk], qf[kk], sacc[sub], 0, 0, 0);
            __builtin_amdgcn_s_setprio(0);
        }

        if (partial) {
            int qrel = (q0 & 32) + l31;
            #pragma unroll
            for (int sub = 0; sub < 2; ++sub)
                #pragma unroll
                for (int r = 0; r < 16; ++r) {
                    int krel = sub * 32 + (r & 3) + 8 * (r >> 2) + 4 * hi;
                    sacc[sub][r] = (krel <= qrel) ? sacc[sub][r] * scale : NEG;
                }
        } else {
            #pragma unroll
            for (int sub = 0; sub < 2; ++sub)
                #pragma unroll
                for (int r = 0; r < 16; ++r) sacc[sub][r] *= scale;
        }

        float pmax = sacc[0][0];
        #pragma unroll
        for (int sub = 0; sub < 2; ++sub)
            #pragma unroll
            for (int r = 0; r < 16; ++r) pmax = fmaxf(pmax, sacc[sub][r]);
        pmax = fmaxf(pmax, __shfl_xor(pmax, 32));
        float mnew = fmaxf(m, pmax);
        float corr = __expf(m - mnew);
        float ps = 0.f;
        #pragma unroll
        for (int sub = 0; sub < 2; ++sub)
            #pragma unroll
            for (int r = 0; r < 16; ++r) {
                float pe = __expf(sacc[sub][r] - mnew);
                sacc[sub][r] = pe;
                ps += pe;
            }
        ps += __shfl_xor(ps, 32);
        ll = ll * corr + ps;
        m = mnew;
        #pragma unroll
        for (int dc = 0; dc < 4; ++dc)
            #pragma unroll
            for (int r = 0; r < 16; ++r) oacc[dc][r] *= corr;

        bf16x8 pf[4];
        #pragma unroll
        for (int sub = 0; sub < 2; ++sub)
            #pragma unroll
            for (int grp = 0; grp < 2; ++grp) {
                int b0 = grp * 8;
                unsigned a  = pack2(sacc[sub][b0 + 0], sacc[sub][b0 + 1]);
                unsigned b_ = pack2(sacc[sub][b0 + 2], sacc[sub][b0 + 3]);
                unsigned c  = pack2(sacc[sub][b0 + 4], sacc[sub][b0 + 5]);
                unsigned d_ = pack2(sacc[sub][b0 + 6], sacc[sub][b0 + 7]);
                unsigned ta = __shfl_xor(a, 32), tb = __shfl_xor(b_, 32);
                unsigned tc = __shfl_xor(c, 32), td = __shfl_xor(d_, 32);
                unsigned w0 = hi ? tc : a;
                unsigned w1 = hi ? td : b_;
                unsigned w2 = hi ? c : ta;
                unsigned w3 = hi ? d_ : tb;
                union { unsigned u[4]; bf16x8 v; } pk;
                pk.u[0] = w0; pk.u[1] = w1; pk.u[2] = w2; pk.u[3] = w3;
                pf[sub * 2 + grp] = pk.v;
            }

        __builtin_amdgcn_s_setprio(1);
        #pragma unroll
        for (int dc = 0; dc < 4; ++dc)
            #pragma unroll
            for (int g2 = 0; g2 < 4; ++g2)
                oacc[dc] = __builtin_amdgcn_mfma_f32_32x32x16_bf16(vf[dc * 4 + g2], pf[g2], oacc[dc], 0, 0, 0);
        __builtin_amdgcn_s_setprio(0);
    }

    float inv = 1.f / ll;
    int qrow = q0 + l31;
    unsigned short* cb = ctx + (size_t)qrow * 4096 + h * 128;
    #pragma unroll
    for (int dc = 0; dc < 4; ++dc)
        #pragma unroll
        for (int r = 0; r < 16; ++r) {
            int d = dc * 32 + (r & 3) + 8 * (r >> 2) + 4 * hi;
            cb[d] = f2b(oacc[dc][r] * inv);
        }
}

extern "C" void kernel_launch(void* const* d_in, const int* in_sizes, int n_in,
                              void* d_out, int out_size, void* d_ws, size_t ws_size,
                              hipStream_t stream) {
    const float* hs  = (const float*)d_in[0];
    const int* tt    = (const int*)d_in[1];
    const int* pos   = (const int*)d_in[2];
    const float* wqv = (const float*)d_in[3];
    const float* wql = (const float*)d_in[4];
    const float* wov = (const float*)d_in[5];
    const float* wol = (const float*)d_in[6];
    const float* invf= (const float*)d_in[7];
    float* out = (float*)d_out;

    const int S = 2048, D = 4096, K = 4096, N3 = 12288;

    char* ws = (char*)d_ws;
    size_t off = 0;
    auto alloc = [&](size_t bytes) {
        void* p = ws + off;
        off += (bytes + 255) & ~(size_t)255;
        return p;
    };
    unsigned char* mask = (unsigned char*)alloc(S);
    float* ct = (float*)alloc((size_t)S * 64 * 4);
    float* st = (float*)alloc((size_t)S * 64 * 4);
    unsigned short* hbf  = (unsigned short*)alloc((size_t)S * D * 2);
    unsigned short* qkv  = (unsigned short*)alloc((size_t)S * N3 * 2);
    unsigned short* vt   = (unsigned short*)alloc((size_t)S * D * 2);
    unsigned short* ctx  = (unsigned short*)alloc((size_t)S * D * 2);
    unsigned short* wqvb = (unsigned short*)alloc((size_t)N3 * K * 2);
    unsigned short* wqlb = (unsigned short*)alloc((size_t)N3 * K * 2);
    unsigned short* wovb = (unsigned short*)alloc((size_t)D * K * 2);
    unsigned short* wolb = (unsigned short*)alloc((size_t)D * K * 2);
    (void)ws_size; (void)n_in; (void)in_sizes; (void)out_size;

    // prep + hs + QKV-weight converts, one BW-bound launch
    prep_cvt<<<16384, 256, 0, stream>>>(tt, pos, invf, mask, ct, st, S,
                                        hs, hbf, (long)S * D,
                                        wqv, wqvb, wql, wqlb, (long)N3 * K);

    // dual-expert QKV (round-11 proven): n fastest, (expert,m) on y
    gemm_bt_dual<1><<<dim3(96, 32), 256, 0, stream>>>(hbf, wqvb, wqlb, qkv, S, N3, K, mask);

    rope_kernel<<<(S * 32 * 16 + 255) / 256, 256, 0, stream>>>(qkv, ct, st, S);
    transpose_v<<<dim3(S / 64, D / 64), 256, 0, stream>>>(qkv, vt, S);

    // attn (1024 blocks) + fused out-proj weight converts (1536 blocks)
    attn32<<<2560, 128, 0, stream>>>(qkv, vt, ctx, S, wov, wovb, wol, wolb, (long)D * K);

    gemm_bt_dual<0><<<dim3(32, 32), 256, 0, stream>>>(ctx, wovb, wolb, out, S, D, K, mask);
}

// Round 19
// 678.865 us; speedup vs baseline: 1.0129x; 1.0129x over previous
//
#include <hip/hip_runtime.h>

typedef __bf16 bf16x8 __attribute__((ext_vector_type(8)));
typedef float f32x4 __attribute__((ext_vector_type(4)));
typedef float f32x16 __attribute__((ext_vector_type(16)));
typedef short short8 __attribute__((ext_vector_type(8)));

union S8 { short8 v; unsigned short u[8]; };

__device__ __forceinline__ float b2f(unsigned short u) {
    unsigned int x = ((unsigned int)u) << 16;
    float f; __builtin_memcpy(&f, &x, 4); return f;
}
__device__ __forceinline__ unsigned short f2b(float f) {
    unsigned int x; __builtin_memcpy(&x, &f, 4);
    unsigned int r = x + 0x7fffu + ((x >> 16) & 1u);   // RNE
    return (unsigned short)(r >> 16);
}
__device__ __forceinline__ unsigned pack2(float lo, float hi) {
    return (unsigned)f2b(lo) | ((unsigned)f2b(hi) << 16);
}

__device__ __forceinline__ void gload_lds16(const unsigned short* g, unsigned short* l) {
    __builtin_amdgcn_global_load_lds(
        (const __attribute__((address_space(1))) void*)g,
        (__attribute__((address_space(3))) void*)l, 16, 0, 0);
}

// ---------------- prep: vis mask + cos/sin tables ----------------
__global__ void prep_kernel(const int* __restrict__ tt, const int* __restrict__ pos,
                            const float* __restrict__ invf,
                            unsigned char* __restrict__ mask,
                            float* __restrict__ ct, float* __restrict__ st, int S) {
    int i = blockIdx.x * 256 + threadIdx.x;
    if (i >= S * 64) return;
    int s = i >> 6, d = i & 63;
    float f = (float)pos[s] * invf[d];
    ct[i] = cosf(f);
    st[i] = sinf(f);
    if (d == 0) mask[s] = (s < S - 1 && tt[s] == 1 && tt[s + 1] == 1) ? 1 : 0;
}

// ---------------- f32 -> bf16 convert (vectorized, grid-stride) ----------------
__global__ void cvt_f32_bf16(const float* __restrict__ in, unsigned short* __restrict__ out, long n) {
    long i = ((long)blockIdx.x * blockDim.x + threadIdx.x) * 4;
    long stride = (long)gridDim.x * blockDim.x * 4;
    for (; i < n; i += stride) {
        float4 v = *(const float4*)(in + i);
        ushort4 u;
        u.x = f2b(v.x); u.y = f2b(v.y); u.z = f2b(v.z); u.w = f2b(v.w);
        *(ushort4*)(out + i) = u;
    }
}

// ---------------- RoPE in-place on bf16 qkv ----------------
__global__ void rope_kernel(unsigned short* __restrict__ qkv,
                            const float* __restrict__ ct, const float* __restrict__ st, int S) {
    int i = blockIdx.x * 256 + threadIdx.x;
    if (i >= S * 32 * 2 * 8) return;
    int c  = i & 7;
    int qk = (i >> 3) & 1;
    int h  = (i >> 4) & 31;
    int s  = i >> 9;
    size_t base = (size_t)s * 12288 + (size_t)qk * 4096 + h * 128 + c * 8;
    S8 x1, x2, y1, y2;
    x1.v = *(const short8*)(qkv + base);
    x2.v = *(const short8*)(qkv + base + 64);
    #pragma unroll
    for (int j = 0; j < 8; ++j) {
        float cc = ct[s * 64 + c * 8 + j];
        float ss = st[s * 64 + c * 8 + j];
        float a = b2f(x1.u[j]), b = b2f(x2.u[j]);
        y1.u[j] = f2b(a * cc - b * ss);
        y2.u[j] = f2b(b * cc + a * ss);
    }
    *(short8*)(qkv + base)      = y1.v;
    *(short8*)(qkv + base + 64) = y2.v;
}

// ---------------- V transpose: qkv v-part [S][4096] -> vt [4096][S] ----------------
__global__ void transpose_v(const unsigned short* __restrict__ qkv,
                            unsigned short* __restrict__ vt, int S) {
    __shared__ unsigned short tile[64][72];
    int s0 = blockIdx.x * 64;
    int hd0 = blockIdx.y * 64;
    int t = threadIdx.x;
    #pragma unroll
    for (int it = 0; it < 2; ++it) {
        int c = it * 256 + t;
        int sl = c >> 3, k8 = (c & 7) << 3;
        S8 v; v.v = *(const short8*)(qkv + (size_t)(s0 + sl) * 12288 + 8192 + hd0 + k8);
        #pragma unroll
        for (int j = 0; j < 8; ++j) tile[sl][k8 + j] = v.u[j];
    }
    __syncthreads();
    #pragma unroll
    for (int it = 0; it < 2; ++it) {
        int c = it * 256 + t;
        int hdl = c >> 3, sk = (c & 7) << 3;
        S8 o;
        #pragma unroll
        for (int j = 0; j < 8; ++j) o.u[j] = tile[sk + j][hdl];
        *(short8*)(vt + (size_t)(hd0 + hdl) * S + s0 + sk) = o.v;
    }
}

// ---------------- dual-expert masked GEMM (proven 2-phase dbuf inner loop) ----------------
// One launch covers BOTH experts: blockIdx.y in [0,32): expert = y>>4, m-tile = y&15.
// C[m][n] = sum_k A[m][k]*B[n][k], stores only rows where mask matches the expert.
template <int OUT_BF16>
__global__ void __launch_bounds__(256, 2)
gemm_bt_dual(const unsigned short* __restrict__ A,
             const unsigned short* __restrict__ Bv,
             const unsigned short* __restrict__ Bl,
             void* __restrict__ Cv,
             int M, int N, int K,
             const unsigned char* __restrict__ mask) {
    __shared__ unsigned short sA[2 * 128 * 32];
    __shared__ unsigned short sB[2 * 128 * 32];
    __shared__ int s_any;
    int t = threadIdx.x;
    int expert = blockIdx.y >> 4;
    int m0 = (blockIdx.y & 15) * 128;
    int n0 = blockIdx.x * 128;
    int want = expert ? 0 : 1;
    const unsigned short* B = expert ? Bl : Bv;

    if (t == 0) s_any = 0;
    __syncthreads();
    if (t < 128 && mask[m0 + t] == (unsigned char)want) s_any = 1;
    __syncthreads();
    if (!s_any) return;

    int lane = t & 63;
    int w = t >> 6;
    int wm = w >> 1, wn = w & 1;
    int l15 = lane & 15, g = lane >> 4;

    int c0 = w * 2, c1 = c0 + 1;
    int r0 = c0 * 16 + (lane >> 2);
    int r1 = c1 * 16 + (lane >> 2);
    int pc = lane & 3;
    const unsigned short* gA0 = A + (size_t)(m0 + r0) * K + ((pc ^ ((r0 >> 1) & 3)) << 3);
    const unsigned short* gA1 = A + (size_t)(m0 + r1) * K + ((pc ^ ((r1 >> 1) & 3)) << 3);
    const unsigned short* gB0 = B + (size_t)(n0 + r0) * K + ((pc ^ ((r0 >> 1) & 3)) << 3);
    const unsigned short* gB1 = B + (size_t)(n0 + r1) * K + ((pc ^ ((r1 >> 1) & 3)) << 3);

    auto stage = [&](int buf, int k0) {
        unsigned short* bA = sA + buf * 4096;
        unsigned short* bB = sB + buf * 4096;
        gload_lds16(gA0 + k0, bA + c0 * 512);
        gload_lds16(gA1 + k0, bA + c1 * 512);
        gload_lds16(gB0 + k0, bB + c0 * 512);
        gload_lds16(gB1 + k0, bB + c1 * 512);
    };

    f32x4 acc[4][4];
    #pragma unroll
    for (int i = 0; i < 4; ++i)
        #pragma unroll
        for (int j = 0; j < 4; ++j) acc[i][j] = (f32x4){0.f, 0.f, 0.f, 0.f};

    stage(0, 0);
    __syncthreads();
    int cur = 0;

    for (int k0 = 0; k0 < K; k0 += 32) {
        if (k0 + 32 < K) stage(cur ^ 1, k0 + 32);
        const unsigned short* rA = sA + cur * 4096;
        const unsigned short* rB = sB + cur * 4096;
        bf16x8 af[4], bfr[4];
        #pragma unroll
        for (int i = 0; i < 4; ++i) {
            int ar = wm * 64 + i * 16 + l15;
            int ca = g ^ ((ar >> 1) & 3);
            af[i] = *(const bf16x8*)(rA + ar * 32 + ca * 8);
            int br = wn * 64 + i * 16 + l15;
            int cb = g ^ ((br >> 1) & 3);
            bfr[i] = *(const bf16x8*)(rB + br * 32 + cb * 8);
        }
        #pragma unroll
        for (int i = 0; i < 4; ++i)
            #pragma unroll
            for (int j = 0; j < 4; ++j)
                acc[i][j] = __builtin_amdgcn_mfma_f32_16x16x32_bf16(af[i], bfr[j], acc[i][j], 0, 0, 0);
        __syncthreads();
        cur ^= 1;
    }

    #pragma unroll
    for (int i = 0; i < 4; ++i) {
        int rbase = m0 + wm * 64 + i * 16 + g * 4;
        #pragma unroll
        for (int r = 0; r < 4; ++r) {
            int row = rbase + r;
            if (mask[row] != (unsigned char)want) continue;
            #pragma unroll
            for (int j = 0; j < 4; ++j) {
                int col = n0 + wn * 64 + j * 16 + l15;
                float vv = acc[i][j][r];
                if (OUT_BF16) ((unsigned short*)Cv)[(size_t)row * N + col] = f2b(vv);
                else          ((float*)Cv)[(size_t)row * N + col] = vv;
            }
        }
    }
}

// ---------------- flash attention v8: uniform paired blocks (round-10 proven) ----------------
__global__ void __launch_bounds__(64, 2)
attn32(const unsigned short* __restrict__ qkv,
       const unsigned short* __restrict__ vt,
       unsigned short* __restrict__ ctx, int S) {
    const float scale = 0.08838834764831845f;  // 1/sqrt(128)
    const float NEG = -1e30f;
    int bid = blockIdx.y * gridDim.x + blockIdx.x;   // 0..1023, x fastest
    int xg = bid & 7;                                 // XCD slot
    int j  = bid >> 3;                                // 0..127
    int h  = xg * 4 + (j >> 5);                       // 4 heads per XCD
    int p  = j & 31;                                  // pair index
    int l = threadIdx.x;
    int l31 = l & 31, hi = l >> 5;

    #pragma unroll 1
    for (int pass = 0; pass < 2; ++pass) {
        int qc = pass ? (63 - p) : p;
        int q0 = qc * 32;

        bf16x8 qf[8];
        {
            const unsigned short* qb = qkv + (size_t)(q0 + l31) * 12288 + h * 128 + hi * 8;
            #pragma unroll
            for (int kk = 0; kk < 8; ++kk) qf[kk] = *(const bf16x8*)(qb + kk * 16);
        }

        f32x16 oacc[4];
        #pragma unroll
        for (int dc = 0; dc < 4; ++dc)
            #pragma unroll
            for (int r = 0; r < 16; ++r) oacc[dc][r] = 0.f;
        float m = NEG, ll = 0.f;

        int nfull = q0 >> 6;
        for (int kt = 0; kt <= nfull; ++kt) {
            int kb = kt << 6;
            bool partial = (kt == nfull);

            bf16x8 vf[16];
            #pragma unroll
            for (int dc = 0; dc < 4; ++dc) {
                const unsigned short* vb = vt + (size_t)(h * 128 + dc * 32 + l31) * S + kb + hi * 8;
                #pragma unroll
                for (int g2 = 0; g2 < 4; ++g2)
                    vf[dc * 4 + g2] = *(const bf16x8*)(vb + g2 * 16);
            }

            f32x16 sacc[2];
            #pragma unroll
            for (int sub = 0; sub < 2; ++sub) {
                #pragma unroll
                for (int r = 0; r < 16; ++r) sacc[sub][r] = 0.f;
                const unsigned short* kp = qkv + (size_t)(kb + sub * 32 + l31) * 12288 + 4096 + h * 128 + hi * 8;
                bf16x8 kf[8];
                #pragma unroll
                for (int kk = 0; kk < 8; ++kk) kf[kk] = *(const bf16x8*)(kp + kk * 16);
                __builtin_amdgcn_s_setprio(1);
                #pragma unroll
                for (int kk = 0; kk < 8; ++kk)
                    sacc[sub] = __builtin_amdgcn_mfma_f32_32x32x16_bf16(kf[kk], qf[kk], sacc[sub], 0, 0, 0);
                __builtin_amdgcn_s_setprio(0);
            }

            if (partial) {
                int qrel = (q0 & 32) + l31;
                #pragma unroll
                for (int sub = 0; sub < 2; ++sub)
                    #pragma unroll
                    for (int r = 0; r < 16; ++r) {
                        int krel = sub * 32 + (r & 3) + 8 * (r >> 2) + 4 * hi;
                        sacc[sub][r] = (krel <= qrel) ? sacc[sub][r] * scale : NEG;
                    }
            } else {
                #pragma unroll
                for (int sub = 0; sub < 2; ++sub)
                    #pragma unroll
                    for (int r = 0; r < 16; ++r) sacc[sub][r] *= scale;
            }

            float pmax = sacc[0][0];
            #pragma unroll
            for (int sub = 0; sub < 2; ++sub)
                #pragma unroll
                for (int r = 0; r < 16; ++r) pmax = fmaxf(pmax, sacc[sub][r]);
            pmax = fmaxf(pmax, __shfl_xor(pmax, 32));
            float mnew = fmaxf(m, pmax);
            float corr = __expf(m - mnew);
            float ps = 0.f;
            #pragma unroll
            for (int sub = 0; sub < 2; ++sub)
                #pragma unroll
                for (int r = 0; r < 16; ++r) {
                    float pe = __expf(sacc[sub][r] - mnew);
                    sacc[sub][r] = pe;
                    ps += pe;
                }
            ps += __shfl_xor(ps, 32);
            ll = ll * corr + ps;
            m = mnew;
            #pragma unroll
            for (int dc = 0; dc < 4; ++dc)
                #pragma unroll
                for (int r = 0; r < 16; ++r) oacc[dc][r] *= corr;

            bf16x8 pf[4];
            #pragma unroll
            for (int sub = 0; sub < 2; ++sub)
                #pragma unroll
                for (int grp = 0; grp < 2; ++grp) {
                    int b0 = grp * 8;
                    unsigned a  = pack2(sacc[sub][b0 + 0], sacc[sub][b0 + 1]);
                    unsigned b_ = pack2(sacc[sub][b0 + 2], sacc[sub][b0 + 3]);
                    unsigned c  = pack2(sacc[sub][b0 + 4], sacc[sub][b0 + 5]);
                    unsigned d_ = pack2(sacc[sub][b0 + 6], sacc[sub][b0 + 7]);
                    unsigned ta = __shfl_xor(a, 32), tb = __shfl_xor(b_, 32);
                    unsigned tc = __shfl_xor(c, 32), td = __shfl_xor(d_, 32);
                    unsigned w0 = hi ? tc : a;
                    unsigned w1 = hi ? td : b_;
                    unsigned w2 = hi ? c : ta;
                    unsigned w3 = hi ? d_ : tb;
                    union { unsigned u[4]; bf16x8 v; } pk;
                    pk.u[0] = w0; pk.u[1] = w1; pk.u[2] = w2; pk.u[3] = w3;
                    pf[sub * 2 + grp] = pk.v;
                }

            __builtin_amdgcn_s_setprio(1);
            #pragma unroll
            for (int dc = 0; dc < 4; ++dc)
                #pragma unroll
                for (int g2 = 0; g2 < 4; ++g2)
                    oacc[dc] = __builtin_amdgcn_mfma_f32_32x32x16_bf16(vf[dc * 4 + g2], pf[g2], oacc[dc], 0, 0, 0);
            __builtin_amdgcn_s_setprio(0);
        }

        float inv = 1.f / ll;
        int qrow = q0 + l31;
        unsigned short* cb = ctx + (size_t)qrow * 4096 + h * 128;
        #pragma unroll
        for (int dc = 0; dc < 4; ++dc)
            #pragma unroll
            for (int r = 0; r < 16; ++r) {
                int d = dc * 32 + (r & 3) + 8 * (r >> 2) + 4 * hi;
                cb[d] = f2b(oacc[dc][r] * inv);
            }
    }
}

extern "C" void kernel_launch(void* const* d_in, const int* in_sizes, int n_in,
                              void* d_out, int out_size, void* d_ws, size_t ws_size,
                              hipStream_t stream) {
    const float* hs  = (const float*)d_in[0];
    const int* tt    = (const int*)d_in[1];
    const int* pos   = (const int*)d_in[2];
    const float* wqv = (const float*)d_in[3];
    const float* wql = (const float*)d_in[4];
    const float* wov = (const float*)d_in[5];
    const float* wol = (const float*)d_in[6];
    const float* invf= (const float*)d_in[7];
    float* out = (float*)d_out;

    const int S = 2048, D = 4096, K = 4096, N3 = 12288;

    char* ws = (char*)d_ws;
    size_t off = 0;
    auto alloc = [&](size_t bytes) {
        void* p = ws + off;
        off += (bytes + 255) & ~(size_t)255;
        return p;
    };
    unsigned char* mask = (unsigned char*)alloc(S);
    float* ct = (float*)alloc((size_t)S * 64 * 4);
    float* st = (float*)alloc((size_t)S * 64 * 4);
    unsigned short* hbf  = (unsigned short*)alloc((size_t)S * D * 2);
    unsigned short* qkv  = (unsigned short*)alloc((size_t)S * N3 * 2);
    unsigned short* vt   = (unsigned short*)alloc((size_t)S * D * 2);
    unsigned short* ctx  = (unsigned short*)alloc((size_t)S * D * 2);
    unsigned short* wqvb = (unsigned short*)alloc((size_t)N3 * K * 2);
    unsigned short* wqlb = (unsigned short*)alloc((size_t)N3 * K * 2);
    unsigned short* wovb = (unsigned short*)alloc((size_t)D * K * 2);
    unsigned short* wolb = (unsigned short*)alloc((size_t)D * K * 2);
    (void)ws_size; (void)n_in; (void)in_sizes; (void)out_size;

    prep_kernel<<<(S * 64 + 255) / 256, 256, 0, stream>>>(tt, pos, invf, mask, ct, st, S);
    cvt_f32_bf16<<<8192, 256, 0, stream>>>(hs, hbf, (long)S * D);

    cvt_f32_bf16<<<16384, 256, 0, stream>>>(wqv, wqvb, (long)N3 * K);
    cvt_f32_bf16<<<16384, 256, 0, stream>>>(wql, wqlb, (long)N3 * K);
    // merged dual-expert QKV: 96 n-tiles x (16 m-tiles x 2 experts)
    gemm_bt_dual<1><<<dim3(96, 32), 256, 0, stream>>>(hbf, wqvb, wqlb, qkv, S, N3, K, mask);

    rope_kernel<<<(S * 32 * 16 + 255) / 256, 256, 0, stream>>>(qkv, ct, st, S);
    transpose_v<<<dim3(S / 64, D / 64), 256, 0, stream>>>(qkv, vt, S);
    attn32<<<dim3(32, 32), 64, 0, stream>>>(qkv, vt, ctx, S);

    cvt_f32_bf16<<<16384, 256, 0, stream>>>(wov, wovb, (long)D * K);
    cvt_f32_bf16<<<16384, 256, 0, stream>>>(wol, wolb, (long)D * K);
    // merged dual-expert out-proj: 32 n-tiles x (16 m-tiles x 2 experts)
    gemm_bt_dual<0><<<dim3(32, 32), 256, 0, stream>>>(ctx, wovb, wolb, out, S, D, K, mask);
}